// Round 1
// baseline (588.519 us; speedup 1.0000x reference)
//
#include <hip/hip_runtime.h>
#include <hip/hip_bf16.h>

#define NN 50000
#define HH 128
#define H2 256
#define EE 800000
#define NBUCK 196          // ceil(NN/256)
#define BINCH 4096         // edges per bin-pass block

typedef _Float16 half8 __attribute__((ext_vector_type(8)));
typedef float float4v __attribute__((ext_vector_type(4)));

__device__ __forceinline__ float bf2f(unsigned short u) {
  union { unsigned int i; float f; } v; v.i = ((unsigned int)u) << 16; return v.f;
}
__device__ __forceinline__ unsigned short f2bf(float f) {
  union { float f; unsigned int i; } v; v.f = f;
  unsigned int x = v.i;
  unsigned int r = x + 0x7fffu + ((x >> 16) & 1u);   // RNE
  return (unsigned short)(r >> 16);
}

// ---------------- dtype detection (fp32 vs bf16 float tensors) ----------------
__global__ void detect_kernel(const unsigned int* __restrict__ val, int* __restrict__ dt) {
  unsigned int w = val[threadIdx.x];
  unsigned short u = (unsigned short)(w & 0xffff);
  int expf = (u >> 7) & 0xff;
  bool match = ((u >> 15) == 0) && expf >= 0x5A && expf <= 0x7E;
  unsigned long long m = __ballot(match);
  if (threadIdx.x == 0) dt[0] = (__popcll(m) >= 48) ? 1 : 0;
}

// ---------------- merged parameter conversion (14 segments, 1 launch) ----------------
// mode 0: f32 out. mode 1: f16 out.
// mode 3: f16 MFMA-fragment-swizzle from row-major [n,k] input (kd=K).
// mode 4: f16 MFMA-fragment-swizzle from [k,n] input (128x128, kd=128).
// Fragment layout: off = (ks*(NC/16) + (n>>4))*512 + ((k>>3&3)*16 + (n&15))*8 + (k&7)
#define NSEG 14
struct ConvSegs {
  const void* s[NSEG];
  void* d[NSEG];
  int n[NSEG];
  int mode[NSEG];
  int kd[NSEG];
  int bstart[NSEG + 1];
};

__global__ __launch_bounds__(256) void convall_kernel(ConvSegs cs, const int* __restrict__ dt) {
  int b = blockIdx.x;
  int seg = 0;
  while (b >= cs.bstart[seg + 1]) ++seg;
  int i = (b - cs.bstart[seg]) * 256 + threadIdx.x;
  if (i >= cs.n[seg]) return;
  float f = dt[0] ? bf2f(((const unsigned short*)cs.s[seg])[i])
                  : ((const float*)cs.s[seg])[i];
  int m = cs.mode[seg];
  if (m == 0) { ((float*)cs.d[seg])[i] = f; return; }
  if (m == 1) { ((_Float16*)cs.d[seg])[i] = (_Float16)f; return; }
  int K = cs.kd[seg];
  int n, k;
  if (m == 3) { n = i / K; k = i - n * K; }
  else        { k = i >> 7; n = i & 127; }
  int NC16 = (cs.n[seg] / K) >> 4;
  int off = ((k >> 5) * NC16 + (n >> 4)) * 512 + (((k >> 3) & 3) * 16 + (n & 15)) * 8 + (k & 7);
  ((_Float16*)cs.d[seg])[off] = (_Float16)f;
}

// ---------------- CSR build: bucket-local ----------------
__global__ __launch_bounds__(256) void bincount_kernel(
    const int* __restrict__ r0, const int* __restrict__ r1,
    int* __restrict__ bcnt, int E) {
  int br = blockIdx.y;
  const int* rows = br ? r1 : r0;
  __shared__ int cnt_s[NBUCK];
  int t = threadIdx.x;
  for (int i = t; i < NBUCK; i += 256) cnt_s[i] = 0;
  __syncthreads();
  int e0 = blockIdx.x * BINCH;
  #pragma unroll
  for (int i = 0; i < 16; ++i) {
    int e = e0 + i * 256 + t;
    if (e < E) atomicAdd(&cnt_s[rows[e] >> 8], 1);
  }
  __syncthreads();
  for (int i = t; i < NBUCK; i += 256) {
    int c = cnt_s[i];
    if (c) atomicAdd(&bcnt[br * NBUCK + i], c);
  }
}

__global__ __launch_bounds__(256) void bscan_kernel(const int* __restrict__ bcnt,
                                                    int* __restrict__ bbase,
                                                    int* __restrict__ gcur) {
  int br = blockIdx.y, t = threadIdx.x;
  __shared__ int s[256];
  int v = (t < NBUCK) ? bcnt[br * NBUCK + t] : 0;
  s[t] = v;
  __syncthreads();
  for (int off = 1; off < 256; off <<= 1) {
    int u = (t >= off) ? s[t - off] : 0;
    __syncthreads();
    s[t] += u;
    __syncthreads();
  }
  int ex = s[t] - v;
  if (t < NBUCK) { bbase[br * NBUCK + t] = ex; gcur[br * NBUCK + t] = ex; }
}

__global__ __launch_bounds__(256) void bin_kernel(
    const int* __restrict__ r0, const int* __restrict__ r1,
    const int* __restrict__ c0, const int* __restrict__ c1,
    const void* __restrict__ v0, const void* __restrict__ v1,
    int* __restrict__ gcur, int2* __restrict__ binned, int E, const int* __restrict__ dt) {
  int br = blockIdx.y;
  const int* rows = br ? r1 : r0;
  const int* cols = br ? c1 : c0;
  const void* vals = br ? v1 : v0;
  int2* bout = binned + (size_t)br * EE;
  int* cur = gcur + br * NBUCK;
  __shared__ int cnt_s[NBUCK];
  __shared__ int base_s[NBUCK];
  int t = threadIdx.x;
  for (int i = t; i < NBUCK; i += 256) cnt_s[i] = 0;
  __syncthreads();
  int e0 = blockIdx.x * BINCH;
  int row[16], col[16], vb[16];
  int cnt = 0;
  bool isb = dt[0] != 0;
  #pragma unroll
  for (int i = 0; i < 16; ++i) {
    int e = e0 + i * 256 + t;
    if (e < E) {
      row[cnt] = rows[e];
      col[cnt] = cols[e];
      float v = isb ? bf2f(((const unsigned short*)vals)[e]) : ((const float*)vals)[e];
      vb[cnt] = __float_as_int(v);
      atomicAdd(&cnt_s[row[cnt] >> 8], 1);
      ++cnt;
    }
  }
  __syncthreads();
  for (int i = t; i < NBUCK; i += 256) {
    int c = cnt_s[i];
    base_s[i] = c ? atomicAdd(&cur[i], c) : 0;
    cnt_s[i] = 0;
  }
  __syncthreads();
  for (int i = 0; i < cnt; ++i) {
    int b = row[i] >> 8;
    int off = atomicAdd(&cnt_s[b], 1);
    bout[base_s[b] + off] = make_int2((row[i] << 16) | col[i], vb[i]);
  }
}

__global__ __launch_bounds__(256) void bucket_kernel(
    const int* __restrict__ bbase, const int2* __restrict__ binned,
    int2* __restrict__ edges, int* __restrict__ rp, int N, int E) {
  int br = blockIdx.y, b = blockIdx.x, t = threadIdx.x;
  const int2* bin = binned + (size_t)br * EE;
  int2* eo = edges + (size_t)br * EE;
  int* r = rp + br * (NN + 1);
  __shared__ int cur[256];
  __shared__ int s[256];
  int base = bbase[br * NBUCK + b];
  int end  = (b + 1 < NBUCK) ? bbase[br * NBUCK + b + 1] : E;
  cur[t] = 0;
  __syncthreads();
  for (int i = base + t; i < end; i += 256)
    atomicAdd(&cur[(((unsigned)bin[i].x) >> 16) & 255], 1);
  __syncthreads();
  int v = cur[t];
  s[t] = v;
  __syncthreads();
  for (int off = 1; off < 256; off <<= 1) {
    int u = (t >= off) ? s[t - off] : 0;
    __syncthreads();
    s[t] += u;
    __syncthreads();
  }
  int ex = base + s[t] - v;
  int row = b * 256 + t;
  if (row < N) r[row] = ex;
  if (b == 0 && t == 0) r[N] = E;
  cur[t] = ex;
  __syncthreads();
  for (int i = base + t; i < end; i += 256) {
    int2 e = bin[i];
    int rl = (((unsigned)e.x) >> 16) & 255;
    int p = atomicAdd(&cur[rl], 1);
    eo[p] = make_int2(e.x & 0xffff, e.y);
  }
}

// ---------------- SpMM (layer-1 only): 16-lane group per row, fused bias/relu/l2 ----------------
// (R9 structure: measured 61.5 us; do not "improve")
template<int DO_L2>
__global__ __launch_bounds__(256) void spmm_kernel(
    const int* __restrict__ rp, const int2* __restrict__ edges,
    const _Float16* __restrict__ src, size_t sstride, const float* __restrict__ bias,
    _Float16* __restrict__ dst, size_t dstride, int N)
{
  int br = blockIdx.y;
  rp += br * (NN + 1);
  edges += (size_t)br * EE;
  src += br * sstride;
  dst += br * dstride;
  int g = threadIdx.x >> 4;
  int l = threadIdx.x & 15;
  int r = blockIdx.x * 16 + g;
  if (r >= N) return;
  int kb = rp[r], ke = rp[r + 1];
  float a0[8] = {0,0,0,0,0,0,0,0}, a1[8] = {0,0,0,0,0,0,0,0};
  float a2[8] = {0,0,0,0,0,0,0,0}, a3[8] = {0,0,0,0,0,0,0,0};
  int k = kb;
  for (; k + 3 < ke; k += 4) {
    int2 e0 = edges[k], e1 = edges[k + 1], e2 = edges[k + 2], e3 = edges[k + 3];
    half8 s0 = *(const half8*)(src + (size_t)e0.x * HH + l * 8);
    half8 s1 = *(const half8*)(src + (size_t)e1.x * HH + l * 8);
    half8 s2 = *(const half8*)(src + (size_t)e2.x * HH + l * 8);
    half8 s3 = *(const half8*)(src + (size_t)e3.x * HH + l * 8);
    float v0 = __int_as_float(e0.y), v1 = __int_as_float(e1.y);
    float v2 = __int_as_float(e2.y), v3 = __int_as_float(e3.y);
    #pragma unroll
    for (int j = 0; j < 8; ++j) {
      a0[j] = fmaf(v0, (float)s0[j], a0[j]);
      a1[j] = fmaf(v1, (float)s1[j], a1[j]);
      a2[j] = fmaf(v2, (float)s2[j], a2[j]);
      a3[j] = fmaf(v3, (float)s3[j], a3[j]);
    }
  }
  for (; k < ke; ++k) {
    int2 e0 = edges[k];
    half8 s0 = *(const half8*)(src + (size_t)e0.x * HH + l * 8);
    float v0 = __int_as_float(e0.y);
    #pragma unroll
    for (int j = 0; j < 8; ++j) a0[j] = fmaf(v0, (float)s0[j], a0[j]);
  }
  float x[8];
  #pragma unroll
  for (int j = 0; j < 8; ++j)
    x[j] = fmaxf((a0[j] + a1[j]) + (a2[j] + a3[j]) + bias[l * 8 + j], 0.f);
  if (DO_L2) {
    float ss = 0.f;
    #pragma unroll
    for (int j = 0; j < 8; ++j) ss += x[j] * x[j];
    #pragma unroll
    for (int m = 1; m < 16; m <<= 1) ss += __shfl_xor(ss, m, 64);
    float sc = 1.f / fmaxf(sqrtf(ss), 1e-12f);
    #pragma unroll
    for (int j = 0; j < 8; ++j) x[j] *= sc;
  }
  half8 hv;
  #pragma unroll
  for (int j = 0; j < 8; ++j) hv[j] = (_Float16)x[j];
  *(half8*)&dst[(size_t)r * HH + l * 8] = hv;
}

// ---------------- fused merged kernel ----------------
// role 0 (spmm+dense): y = A@x (gather), then x_next = [l2](relu(y @ W + b))
//   via per-block 16x128 MFMA using Wt in fragment-major layout.
//   Uses associativity A@(xW) = (A@x)@W so this launch depends only on x_cur.
// role 1 (score): 64-row tile MLP score into sacc (A-frags read from global x,
//   L1-resident; h1 in LDS). Independent of role 0 -> overlaps spmm latency
//   with MFMA work in the same launch.
// Interleave 4 spmm blocks : 1 score block so CU mix stays constant.
// LDS = 64*264*2 = 33792 B -> 4 blocks/CU; launch_bounds(256,4) caps VGPR 128.
template<int DO_L2>
__global__ __launch_bounds__(256, 4) void fused_kernel(
    const int* __restrict__ rp, const int2* __restrict__ edges,
    const _Float16* __restrict__ xcur, _Float16* __restrict__ xnext,
    const _Float16* __restrict__ wt, const float* __restrict__ bias,
    const _Float16* __restrict__ w1, const _Float16* __restrict__ w2,
    const float* __restrict__ b1v, const float* __restrict__ b2v,
    const float* __restrict__ w3v,
    float* __restrict__ S, int N, int sg, int gx, int nsp)
{
  extern __shared__ _Float16 smem[];
  const size_t XSC = (size_t)(NN + 128) * HH;
  int br = blockIdx.y;
  rp += br * (NN + 1);
  edges += (size_t)br * EE;
  xcur += br * XSC;

  int bx = blockIdx.x;
  int role, idx;
  if (nsp) {
    int q = bx / 5, k5 = bx - q * 5;
    if (k5 < 4) { idx = q * 4 + k5; if (idx >= sg) return; role = 0; }
    else        { idx = q;          if (idx >= gx) return; role = 1; }
  } else { role = 1; idx = bx; if (idx >= gx) return; }

  const int lane = threadIdx.x & 63, w = threadIdx.x >> 6;
  const int lm = lane & 15, lq = lane >> 4;

  if (role == 0) {
    xnext += br * XSC;
    // ---- gather: 16 rows, 16 lanes/row (R9 spmm structure) ----
    int g = threadIdx.x >> 4, l = threadIdx.x & 15;
    int r = idx * 16 + g;                 // N % 16 == 0: no guard needed
    int kb = rp[r], ke = rp[r + 1];
    float a0[8] = {0,0,0,0,0,0,0,0}, a1[8] = {0,0,0,0,0,0,0,0};
    float a2[8] = {0,0,0,0,0,0,0,0}, a3[8] = {0,0,0,0,0,0,0,0};
    int k = kb;
    for (; k + 3 < ke; k += 4) {
      int2 e0 = edges[k], e1 = edges[k + 1], e2 = edges[k + 2], e3 = edges[k + 3];
      half8 s0 = *(const half8*)(xcur + (size_t)e0.x * HH + l * 8);
      half8 s1 = *(const half8*)(xcur + (size_t)e1.x * HH + l * 8);
      half8 s2 = *(const half8*)(xcur + (size_t)e2.x * HH + l * 8);
      half8 s3 = *(const half8*)(xcur + (size_t)e3.x * HH + l * 8);
      float v0 = __int_as_float(e0.y), v1 = __int_as_float(e1.y);
      float v2 = __int_as_float(e2.y), v3 = __int_as_float(e3.y);
      #pragma unroll
      for (int j = 0; j < 8; ++j) {
        a0[j] = fmaf(v0, (float)s0[j], a0[j]);
        a1[j] = fmaf(v1, (float)s1[j], a1[j]);
        a2[j] = fmaf(v2, (float)s2[j], a2[j]);
        a3[j] = fmaf(v3, (float)s3[j], a3[j]);
      }
    }
    for (; k < ke; ++k) {
      int2 e0 = edges[k];
      half8 s0 = *(const half8*)(xcur + (size_t)e0.x * HH + l * 8);
      float v0 = __int_as_float(e0.y);
      #pragma unroll
      for (int j = 0; j < 8; ++j) a0[j] = fmaf(v0, (float)s0[j], a0[j]);
    }
    half8 hv;
    #pragma unroll
    for (int j = 0; j < 8; ++j)
      hv[j] = (_Float16)((a0[j] + a1[j]) + (a2[j] + a3[j]));
    *(half8*)&smem[g * 136 + l * 8] = hv;     // y tile [16][128], stride 136
    __syncthreads();

    // ---- dense epilogue: 16x128 @ 128x128, wave w owns n-tiles {2w, 2w+1} ----
    float4v acc[2];
    acc[0] = (float4v){0.f,0.f,0.f,0.f};
    acc[1] = (float4v){0.f,0.f,0.f,0.f};
    #pragma unroll
    for (int k0 = 0; k0 < HH; k0 += 32) {
      half8 ah = *(const half8*)&smem[lm * 136 + k0 + lq * 8];
      #pragma unroll
      for (int nt = 0; nt < 2; ++nt) {
        half8 bh = *(const half8*)(wt + (((k0 >> 5) * 8) + w * 2 + nt) * 512 + lane * 8);
        acc[nt] = __builtin_amdgcn_mfma_f32_16x16x32_f16(ah, bh, acc[nt], 0, 0, 0);
      }
    }
    float v[2][4];
    float ssp[4] = {0.f, 0.f, 0.f, 0.f};
    #pragma unroll
    for (int nt = 0; nt < 2; ++nt) {
      float bv = bias[w * 32 + nt * 16 + lm];
      #pragma unroll
      for (int rr = 0; rr < 4; ++rr) {
        float t = fmaxf(acc[nt][rr] + bv, 0.f);
        v[nt][rr] = t;
        ssp[rr] += t * t;
      }
    }
    if (DO_L2) {
      #pragma unroll
      for (int m = 1; m < 16; m <<= 1) {
        #pragma unroll
        for (int rr = 0; rr < 4; ++rr) ssp[rr] += __shfl_xor(ssp[rr], m, 64);
      }
      float* sred = (float*)(smem + 16 * 136);       // 64 floats
      if (lm == 0) {
        #pragma unroll
        for (int rr = 0; rr < 4; ++rr) sred[w * 16 + lq * 4 + rr] = ssp[rr];
      }
      __syncthreads();
      #pragma unroll
      for (int rr = 0; rr < 4; ++rr) {
        int rowl = lq * 4 + rr;
        float tot = sred[rowl] + sred[16 + rowl] + sred[32 + rowl] + sred[48 + rowl];
        float sc = 1.f / fmaxf(sqrtf(tot), 1e-12f);
        v[0][rr] *= sc;
        v[1][rr] *= sc;
      }
    }
    #pragma unroll
    for (int rr = 0; rr < 4; ++rr) {
      size_t ro = (size_t)(idx * 16 + lq * 4 + rr) * HH;
      #pragma unroll
      for (int nt = 0; nt < 2; ++nt)
        xnext[ro + w * 32 + nt * 16 + lm] = (_Float16)v[nt][rr];
    }
    return;
  }

  // ---- score role: 64-row tile, wave w owns 64 n-cols ----
  float* Sb = S + (size_t)br * N;
  _Float16* h1s = smem;                 // [64][264]
  const int HS = H2 + 8;
  const int m0 = idx * 64;
  const int wn = w * 64;
  {
    float4v acc[4][4];
    #pragma unroll
    for (int i = 0; i < 4; ++i)
      #pragma unroll
      for (int j = 0; j < 4; ++j) acc[i][j] = (float4v){0.f,0.f,0.f,0.f};
    #pragma unroll
    for (int k0 = 0; k0 < HH; k0 += 32) {
      half8 ah[4], bh[4];
      #pragma unroll
      for (int mt = 0; mt < 4; ++mt)
        ah[mt] = *(const half8*)(xcur + (size_t)(m0 + mt * 16 + lm) * HH + k0 + lq * 8);
      #pragma unroll
      for (int nt = 0; nt < 4; ++nt)
        bh[nt] = *(const half8*)(w1 + (((k0 >> 5) * 16) + (wn >> 4) + nt) * 512 + lane * 8);
      #pragma unroll
      for (int mt = 0; mt < 4; ++mt)
        #pragma unroll
        for (int nt = 0; nt < 4; ++nt)
          acc[mt][nt] = __builtin_amdgcn_mfma_f32_16x16x32_f16(ah[mt], bh[nt], acc[mt][nt], 0, 0, 0);
    }
    float bv[4];
    #pragma unroll
    for (int nt = 0; nt < 4; ++nt) bv[nt] = b1v[wn + nt * 16 + lm];
    #pragma unroll
    for (int mt = 0; mt < 4; ++mt)
      #pragma unroll
      for (int rr = 0; rr < 4; ++rr) {
        int rowl = mt * 16 + lq * 4 + rr;
        #pragma unroll
        for (int nt = 0; nt < 4; ++nt)
          h1s[rowl * HS + wn + nt * 16 + lm] = (_Float16)fmaxf(acc[mt][nt][rr] + bv[nt], 0.f);
      }
  }
  __syncthreads();
  {
    float4v acc[4][4];
    #pragma unroll
    for (int i = 0; i < 4; ++i)
      #pragma unroll
      for (int j = 0; j < 4; ++j) acc[i][j] = (float4v){0.f,0.f,0.f,0.f};
    #pragma unroll
    for (int k0 = 0; k0 < H2; k0 += 32) {
      half8 ah[4], bh[4];
      #pragma unroll
      for (int mt = 0; mt < 4; ++mt)
        ah[mt] = *(const half8*)&h1s[(mt * 16 + lm) * HS + k0 + lq * 8];
      #pragma unroll
      for (int nt = 0; nt < 4; ++nt)
        bh[nt] = *(const half8*)(w2 + (((k0 >> 5) * 16) + (wn >> 4) + nt) * 512 + lane * 8);
      #pragma unroll
      for (int mt = 0; mt < 4; ++mt)
        #pragma unroll
        for (int nt = 0; nt < 4; ++nt)
          acc[mt][nt] = __builtin_amdgcn_mfma_f32_16x16x32_f16(ah[mt], bh[nt], acc[mt][nt], 0, 0, 0);
    }
    float bv[4], wv[4];
    #pragma unroll
    for (int nt = 0; nt < 4; ++nt) {
      int col = wn + nt * 16 + lm;
      bv[nt] = b2v[col]; wv[nt] = w3v[col];
    }
    #pragma unroll
    for (int mt = 0; mt < 4; ++mt)
      #pragma unroll
      for (int rr = 0; rr < 4; ++rr) {
        float p = 0.f;
        #pragma unroll
        for (int nt = 0; nt < 4; ++nt)
          p += fmaxf(acc[mt][nt][rr] + bv[nt], 0.f) * wv[nt];
        p += __shfl_xor(p, 1, 64);
        p += __shfl_xor(p, 2, 64);
        p += __shfl_xor(p, 4, 64);
        p += __shfl_xor(p, 8, 64);
        if (lm == 0) {
          int row = m0 + mt * 16 + lq * 4 + rr;
          if (row < N) atomicAdd(&Sb[row], p);
        }
      }
  }
}

__global__ void final_kernel(const float* __restrict__ s_in, const float* __restrict__ s_out,
                             const float* __restrict__ b3, void* __restrict__ out, int N,
                             const int* __restrict__ dt) {
  int i = blockIdx.x * 256 + threadIdx.x;
  if (i >= N) return;
  float b = 4.f * b3[0];
  float v = (s_in[i] + b) * (s_out[i] + b);
  if (dt[0]) ((unsigned short*)out)[i] = f2bf(v);
  else       ((float*)out)[i] = v;
}

extern "C" void kernel_launch(void* const* d_in, const int* in_sizes, int n_in,
                              void* d_out, int out_size, void* d_ws, size_t ws_size,
                              hipStream_t stream) {
  const int N = NN, E = EE;

  char* ws = (char*)d_ws;
  size_t o = 0;
  auto alloc = [&](size_t bytes) -> void* {
    void* p = ws + o;
    o = (o + bytes + 255) & ~(size_t)255;
    return p;
  };

  int* dt = (int*)alloc(16);
  float* bc[4]; float* l1b; float* l2b; float* w3f; float* l3b;
  for (int i = 0; i < 4; ++i) bc[i] = (float*)alloc(HH * 4);
  l1b = (float*)alloc(H2 * 4);
  l2b = (float*)alloc(H2 * 4);
  w3f = (float*)alloc(H2 * 4);
  l3b = (float*)alloc(4);
  _Float16* l1w_h = (_Float16*)alloc(H2 * HH * 2);
  _Float16* l2w_h = (_Float16*)alloc(H2 * H2 * 2);
  _Float16* Wt_h[3];
  for (int i = 0; i < 3; ++i) Wt_h[i] = (_Float16*)alloc(HH * HH * 2);
  _Float16* w1_h = (_Float16*)alloc((size_t)N * HH * 2);

  const int NP = N + 128;
  const size_t XS = (size_t)NP * HH;
  int* rp    = (int*)alloc(2 * (size_t)(N + 1) * 4);
  int* bcnt  = (int*)alloc(2 * NBUCK * 4);
  int* bbase = (int*)alloc(2 * NBUCK * 4);
  int* gcur  = (int*)alloc(2 * NBUCK * 4);
  int2* binned = (int2*)alloc(2 * (size_t)E * 8);
  int2* edges  = (int2*)alloc(2 * (size_t)E * 8);
  _Float16* x_h  = (_Float16*)alloc(2 * XS * 2);    // ping
  _Float16* tb_h = (_Float16*)alloc(2 * XS * 2);    // pong
  float* sacc = (float*)alloc(2 * (size_t)N * 4);

  dim3 blk(256);
  detect_kernel<<<1, 64, 0, stream>>>((const unsigned int*)d_in[2], dt);

  // merged conversions (w1/w2/wt in fragment-major layout)
  ConvSegs cs;
  const void* srcs[NSEG] = {d_in[7], d_in[9], d_in[11], d_in[13], d_in[15], d_in[17],
                            d_in[18], d_in[19], d_in[14], d_in[16], d_in[8], d_in[10],
                            d_in[12], d_in[6]};
  void* dsts[NSEG] = {bc[0], bc[1], bc[2], bc[3], l1b, l2b, w3f, l3b,
                      l1w_h, l2w_h, Wt_h[0], Wt_h[1], Wt_h[2], w1_h};
  int ns[NSEG] = {HH, HH, HH, HH, H2, H2, H2, 1,
                  H2 * HH, H2 * H2, HH * HH, HH * HH, HH * HH, N * HH};
  int ms[NSEG] = {0, 0, 0, 0, 0, 0, 0, 0, 3, 3, 4, 4, 4, 1};
  int ks[NSEG] = {0, 0, 0, 0, 0, 0, 0, 0, HH, H2, HH, HH, HH, 0};
  int btot = 0;
  for (int i = 0; i < NSEG; ++i) {
    cs.s[i] = srcs[i]; cs.d[i] = dsts[i]; cs.n[i] = ns[i]; cs.mode[i] = ms[i]; cs.kd[i] = ks[i];
    cs.bstart[i] = btot;
    btot += (ns[i] + 255) / 256;
  }
  cs.bstart[NSEG] = btot;
  convall_kernel<<<btot, blk, 0, stream>>>(cs, dt);

  hipMemsetAsync(sacc, 0, 2 * (size_t)N * 4, stream);
  hipMemsetAsync(bcnt, 0, 2 * NBUCK * 4, stream);
  // zero pad rows (score A-frags read up to 47 rows past N)
  hipMemsetAsync(x_h  + (size_t)N * HH, 0, (size_t)128 * HH * 2, stream);
  hipMemsetAsync(x_h  + XS + (size_t)N * HH, 0, (size_t)128 * HH * 2, stream);
  hipMemsetAsync(tb_h + (size_t)N * HH, 0, (size_t)128 * HH * 2, stream);
  hipMemsetAsync(tb_h + XS + (size_t)N * HH, 0, (size_t)128 * HH * 2, stream);

  int sg   = (N + 15) / 16;          // 3125 spmm row-blocks
  int gx64 = (N + 63) / 64;          // 782 score tiles
  int mg   = ((sg + 3) / 4) * 5;     // 3910: 4 spmm : 1 score interleave
  int bg   = (E + BINCH - 1) / BINCH;
  const size_t FLDS = (size_t)64 * (H2 + 8) * sizeof(_Float16);   // 33792 B

  // ---- CSR build, both branches in parallel ----
  bincount_kernel<<<dim3(bg, 2), blk, 0, stream>>>((const int*)d_in[0], (const int*)d_in[3], bcnt, E);
  bscan_kernel<<<dim3(1, 2), blk, 0, stream>>>(bcnt, bbase, gcur);
  bin_kernel<<<dim3(bg, 2), blk, 0, stream>>>(
      (const int*)d_in[0], (const int*)d_in[3], (const int*)d_in[1], (const int*)d_in[4],
      d_in[2], d_in[5], gcur, binned, E, dt);
  bucket_kernel<<<dim3(NBUCK, 2), blk, 0, stream>>>(bbase, binned, edges, rp, N, E);

  // ---- layer 1: x1 = l2(relu(A@W1 + b1)) ----
  spmm_kernel<1><<<dim3(sg, 2), blk, 0, stream>>>(rp, edges, w1_h, 0, bc[0], x_h, XS, N);

  // ---- layers 2..4 merged with score(x_prev); associativity: A@(xW) = (A@x)@W ----
  fused_kernel<1><<<dim3(mg, 2), blk, FLDS, stream>>>(
      rp, edges, x_h, tb_h, Wt_h[0], bc[1], l1w_h, l2w_h, l1b, l2b, w3f,
      sacc, N, sg, gx64, 1);
  fused_kernel<1><<<dim3(mg, 2), blk, FLDS, stream>>>(
      rp, edges, tb_h, x_h, Wt_h[1], bc[2], l1w_h, l2w_h, l1b, l2b, w3f,
      sacc, N, sg, gx64, 1);
  fused_kernel<0><<<dim3(mg, 2), blk, FLDS, stream>>>(
      rp, edges, x_h, tb_h, Wt_h[2], bc[3], l1w_h, l2w_h, l1b, l2b, w3f,
      sacc, N, sg, gx64, 1);
  // ---- score(x4) only ----
  fused_kernel<0><<<dim3(gx64, 2), blk, FLDS, stream>>>(
      rp, edges, tb_h, nullptr, nullptr, nullptr, l1w_h, l2w_h, l1b, l2b, w3f,
      sacc, N, 0, gx64, 0);

  final_kernel<<<(N + 255) / 256, blk, 0, stream>>>(sacc, sacc + N, l3b, d_out, N, dt);
}

// Round 2
// 560.068 us; speedup vs baseline: 1.0508x; 1.0508x over previous
//
#include <hip/hip_runtime.h>
#include <hip/hip_bf16.h>

#define NN 50000
#define HH 128
#define H2 256
#define EE 800000
#define NBUCK 196          // ceil(NN/256)
#define BINCH 4096         // edges per bin-pass block

typedef _Float16 half8 __attribute__((ext_vector_type(8)));
typedef float float4v __attribute__((ext_vector_type(4)));

__device__ __forceinline__ float bf2f(unsigned short u) {
  union { unsigned int i; float f; } v; v.i = ((unsigned int)u) << 16; return v.f;
}
__device__ __forceinline__ unsigned short f2bf(float f) {
  union { float f; unsigned int i; } v; v.f = f;
  unsigned int x = v.i;
  unsigned int r = x + 0x7fffu + ((x >> 16) & 1u);   // RNE
  return (unsigned short)(r >> 16);
}

// ---------------- dtype detection (fp32 vs bf16 float tensors) ----------------
__global__ void detect_kernel(const unsigned int* __restrict__ val, int* __restrict__ dt) {
  unsigned int w = val[threadIdx.x];
  unsigned short u = (unsigned short)(w & 0xffff);
  int expf = (u >> 7) & 0xff;
  bool match = ((u >> 15) == 0) && expf >= 0x5A && expf <= 0x7E;
  unsigned long long m = __ballot(match);
  if (threadIdx.x == 0) dt[0] = (__popcll(m) >= 48) ? 1 : 0;
}

// ---------------- merged parameter conversion (14 segments, 1 launch) ----------------
// mode 0: f32 out. mode 1: f16 out.
// mode 3: f16 MFMA-fragment-swizzle from row-major [n,k] input (kd=K).
// mode 4: f16 MFMA-fragment-swizzle from [k,n] input (128x128, kd=128).
// Fragment layout: off = (ks*(NC/16) + (n>>4))*512 + ((k>>3&3)*16 + (n&15))*8 + (k&7)
#define NSEG 14
struct ConvSegs {
  const void* s[NSEG];
  void* d[NSEG];
  int n[NSEG];
  int mode[NSEG];
  int kd[NSEG];
  int bstart[NSEG + 1];
};

__global__ __launch_bounds__(256) void convall_kernel(ConvSegs cs, const int* __restrict__ dt) {
  int b = blockIdx.x;
  int seg = 0;
  while (b >= cs.bstart[seg + 1]) ++seg;
  int i = (b - cs.bstart[seg]) * 256 + threadIdx.x;
  if (i >= cs.n[seg]) return;
  float f = dt[0] ? bf2f(((const unsigned short*)cs.s[seg])[i])
                  : ((const float*)cs.s[seg])[i];
  int m = cs.mode[seg];
  if (m == 0) { ((float*)cs.d[seg])[i] = f; return; }
  if (m == 1) { ((_Float16*)cs.d[seg])[i] = (_Float16)f; return; }
  int K = cs.kd[seg];
  int n, k;
  if (m == 3) { n = i / K; k = i - n * K; }
  else        { k = i >> 7; n = i & 127; }
  int NC16 = (cs.n[seg] / K) >> 4;
  int off = ((k >> 5) * NC16 + (n >> 4)) * 512 + (((k >> 3) & 3) * 16 + (n & 15)) * 8 + (k & 7);
  ((_Float16*)cs.d[seg])[off] = (_Float16)f;
}

// ---------------- CSR build: bucket-local ----------------
__global__ __launch_bounds__(256) void bincount_kernel(
    const int* __restrict__ r0, const int* __restrict__ r1,
    int* __restrict__ bcnt, int E) {
  int br = blockIdx.y;
  const int* rows = br ? r1 : r0;
  __shared__ int cnt_s[NBUCK];
  int t = threadIdx.x;
  for (int i = t; i < NBUCK; i += 256) cnt_s[i] = 0;
  __syncthreads();
  int e0 = blockIdx.x * BINCH;
  #pragma unroll
  for (int i = 0; i < 16; ++i) {
    int e = e0 + i * 256 + t;
    if (e < E) atomicAdd(&cnt_s[rows[e] >> 8], 1);
  }
  __syncthreads();
  for (int i = t; i < NBUCK; i += 256) {
    int c = cnt_s[i];
    if (c) atomicAdd(&bcnt[br * NBUCK + i], c);
  }
}

__global__ __launch_bounds__(256) void bscan_kernel(const int* __restrict__ bcnt,
                                                    int* __restrict__ bbase,
                                                    int* __restrict__ gcur) {
  int br = blockIdx.y, t = threadIdx.x;
  __shared__ int s[256];
  int v = (t < NBUCK) ? bcnt[br * NBUCK + t] : 0;
  s[t] = v;
  __syncthreads();
  for (int off = 1; off < 256; off <<= 1) {
    int u = (t >= off) ? s[t - off] : 0;
    __syncthreads();
    s[t] += u;
    __syncthreads();
  }
  int ex = s[t] - v;
  if (t < NBUCK) { bbase[br * NBUCK + t] = ex; gcur[br * NBUCK + t] = ex; }
}

__global__ __launch_bounds__(256) void bin_kernel(
    const int* __restrict__ r0, const int* __restrict__ r1,
    const int* __restrict__ c0, const int* __restrict__ c1,
    const void* __restrict__ v0, const void* __restrict__ v1,
    int* __restrict__ gcur, int2* __restrict__ binned, int E, const int* __restrict__ dt) {
  int br = blockIdx.y;
  const int* rows = br ? r1 : r0;
  const int* cols = br ? c1 : c0;
  const void* vals = br ? v1 : v0;
  int2* bout = binned + (size_t)br * EE;
  int* cur = gcur + br * NBUCK;
  __shared__ int cnt_s[NBUCK];
  __shared__ int base_s[NBUCK];
  int t = threadIdx.x;
  for (int i = t; i < NBUCK; i += 256) cnt_s[i] = 0;
  __syncthreads();
  int e0 = blockIdx.x * BINCH;
  int row[16], col[16], vb[16];
  int cnt = 0;
  bool isb = dt[0] != 0;
  #pragma unroll
  for (int i = 0; i < 16; ++i) {
    int e = e0 + i * 256 + t;
    if (e < E) {
      row[cnt] = rows[e];
      col[cnt] = cols[e];
      float v = isb ? bf2f(((const unsigned short*)vals)[e]) : ((const float*)vals)[e];
      vb[cnt] = __float_as_int(v);
      atomicAdd(&cnt_s[row[cnt] >> 8], 1);
      ++cnt;
    }
  }
  __syncthreads();
  for (int i = t; i < NBUCK; i += 256) {
    int c = cnt_s[i];
    base_s[i] = c ? atomicAdd(&cur[i], c) : 0;
    cnt_s[i] = 0;
  }
  __syncthreads();
  for (int i = 0; i < cnt; ++i) {
    int b = row[i] >> 8;
    int off = atomicAdd(&cnt_s[b], 1);
    bout[base_s[b] + off] = make_int2((row[i] << 16) | col[i], vb[i]);
  }
}

__global__ __launch_bounds__(256) void bucket_kernel(
    const int* __restrict__ bbase, const int2* __restrict__ binned,
    int2* __restrict__ edges, int* __restrict__ rp, int N, int E) {
  int br = blockIdx.y, b = blockIdx.x, t = threadIdx.x;
  const int2* bin = binned + (size_t)br * EE;
  int2* eo = edges + (size_t)br * EE;
  int* r = rp + br * (NN + 1);
  __shared__ int cur[256];
  __shared__ int s[256];
  int base = bbase[br * NBUCK + b];
  int end  = (b + 1 < NBUCK) ? bbase[br * NBUCK + b + 1] : E;
  cur[t] = 0;
  __syncthreads();
  for (int i = base + t; i < end; i += 256)
    atomicAdd(&cur[(((unsigned)bin[i].x) >> 16) & 255], 1);
  __syncthreads();
  int v = cur[t];
  s[t] = v;
  __syncthreads();
  for (int off = 1; off < 256; off <<= 1) {
    int u = (t >= off) ? s[t - off] : 0;
    __syncthreads();
    s[t] += u;
    __syncthreads();
  }
  int ex = base + s[t] - v;
  int row = b * 256 + t;
  if (row < N) r[row] = ex;
  if (b == 0 && t == 0) r[N] = E;
  cur[t] = ex;
  __syncthreads();
  for (int i = base + t; i < end; i += 256) {
    int2 e = bin[i];
    int rl = (((unsigned)e.x) >> 16) & 255;
    int p = atomicAdd(&cur[rl], 1);
    eo[p] = make_int2(e.x & 0xffff, e.y);
  }
}

// ---------------- SpMM (layer-1 only): 16-lane group per row, fused bias/relu/l2 ----------------
// (R9 structure: measured 61.5 us; do not "improve")
template<int DO_L2>
__global__ __launch_bounds__(256) void spmm_kernel(
    const int* __restrict__ rp, const int2* __restrict__ edges,
    const _Float16* __restrict__ src, size_t sstride, const float* __restrict__ bias,
    _Float16* __restrict__ dst, size_t dstride, int N)
{
  int br = blockIdx.y;
  rp += br * (NN + 1);
  edges += (size_t)br * EE;
  src += br * sstride;
  dst += br * dstride;
  int g = threadIdx.x >> 4;
  int l = threadIdx.x & 15;
  int r = blockIdx.x * 16 + g;
  if (r >= N) return;
  int kb = rp[r], ke = rp[r + 1];
  float a0[8] = {0,0,0,0,0,0,0,0}, a1[8] = {0,0,0,0,0,0,0,0};
  float a2[8] = {0,0,0,0,0,0,0,0}, a3[8] = {0,0,0,0,0,0,0,0};
  int k = kb;
  for (; k + 3 < ke; k += 4) {
    int2 e0 = edges[k], e1 = edges[k + 1], e2 = edges[k + 2], e3 = edges[k + 3];
    half8 s0 = *(const half8*)(src + (size_t)e0.x * HH + l * 8);
    half8 s1 = *(const half8*)(src + (size_t)e1.x * HH + l * 8);
    half8 s2 = *(const half8*)(src + (size_t)e2.x * HH + l * 8);
    half8 s3 = *(const half8*)(src + (size_t)e3.x * HH + l * 8);
    float v0 = __int_as_float(e0.y), v1 = __int_as_float(e1.y);
    float v2 = __int_as_float(e2.y), v3 = __int_as_float(e3.y);
    #pragma unroll
    for (int j = 0; j < 8; ++j) {
      a0[j] = fmaf(v0, (float)s0[j], a0[j]);
      a1[j] = fmaf(v1, (float)s1[j], a1[j]);
      a2[j] = fmaf(v2, (float)s2[j], a2[j]);
      a3[j] = fmaf(v3, (float)s3[j], a3[j]);
    }
  }
  for (; k < ke; ++k) {
    int2 e0 = edges[k];
    half8 s0 = *(const half8*)(src + (size_t)e0.x * HH + l * 8);
    float v0 = __int_as_float(e0.y);
    #pragma unroll
    for (int j = 0; j < 8; ++j) a0[j] = fmaf(v0, (float)s0[j], a0[j]);
  }
  float x[8];
  #pragma unroll
  for (int j = 0; j < 8; ++j)
    x[j] = fmaxf((a0[j] + a1[j]) + (a2[j] + a3[j]) + bias[l * 8 + j], 0.f);
  if (DO_L2) {
    float ss = 0.f;
    #pragma unroll
    for (int j = 0; j < 8; ++j) ss += x[j] * x[j];
    #pragma unroll
    for (int m = 1; m < 16; m <<= 1) ss += __shfl_xor(ss, m, 64);
    float sc = 1.f / fmaxf(sqrtf(ss), 1e-12f);
    #pragma unroll
    for (int j = 0; j < 8; ++j) x[j] *= sc;
  }
  half8 hv;
  #pragma unroll
  for (int j = 0; j < 8; ++j) hv[j] = (_Float16)x[j];
  *(half8*)&dst[(size_t)r * HH + l * 8] = hv;
}

// ---------------- fused merged kernel ----------------
// role 0 (spmm+dense): y = A@x (gather), then x_next = [l2](relu(y @ W + b))
//   via per-block 16x128 MFMA using Wt in fragment-major layout.
//   Uses associativity A@(xW) = (A@x)@W so this launch depends only on x_cur.
// role 1 (score): 32-row tile MLP score into sacc (A-frags read from global x,
//   L1/L2-resident; h1 in LDS). Independent of role 0 -> overlaps spmm latency
//   with MFMA work in the same launch.
// R1 occupancy fix: 32-row score tile (LDS 16896 B, was 33792) +
// __launch_bounds__(256,6) so ~6 blocks/CU co-reside (was ~3) — the gather
// is latency-bound and needs the waves. Interleave 2 spmm : 1 score.
template<int DO_L2>
__global__ __launch_bounds__(256, 6) void fused_kernel(
    const int* __restrict__ rp, const int2* __restrict__ edges,
    const _Float16* __restrict__ xcur, _Float16* __restrict__ xnext,
    const _Float16* __restrict__ wt, const float* __restrict__ bias,
    const _Float16* __restrict__ w1, const _Float16* __restrict__ w2,
    const float* __restrict__ b1v, const float* __restrict__ b2v,
    const float* __restrict__ w3v,
    float* __restrict__ S, int N, int sg, int gx, int nsp)
{
  extern __shared__ _Float16 smem[];
  const size_t XSC = (size_t)(NN + 128) * HH;
  int br = blockIdx.y;
  rp += br * (NN + 1);
  edges += (size_t)br * EE;
  xcur += br * XSC;

  int bx = blockIdx.x;
  int role, idx;
  if (nsp) {
    int q = bx / 3, k3 = bx - q * 3;
    if (k3 < 2) { idx = q * 2 + k3; if (idx >= sg) return; role = 0; }
    else        { idx = q;          if (idx >= gx) return; role = 1; }
  } else { role = 1; idx = bx; if (idx >= gx) return; }

  const int lane = threadIdx.x & 63, w = threadIdx.x >> 6;
  const int lm = lane & 15, lq = lane >> 4;

  if (role == 0) {
    xnext += br * XSC;
    // ---- gather: 16 rows, 16 lanes/row (R9 spmm structure) ----
    int g = threadIdx.x >> 4, l = threadIdx.x & 15;
    int r = idx * 16 + g;                 // N % 16 == 0: no guard needed
    int kb = rp[r], ke = rp[r + 1];
    float a0[8] = {0,0,0,0,0,0,0,0}, a1[8] = {0,0,0,0,0,0,0,0};
    float a2[8] = {0,0,0,0,0,0,0,0}, a3[8] = {0,0,0,0,0,0,0,0};
    int k = kb;
    for (; k + 3 < ke; k += 4) {
      int2 e0 = edges[k], e1 = edges[k + 1], e2 = edges[k + 2], e3 = edges[k + 3];
      half8 s0 = *(const half8*)(xcur + (size_t)e0.x * HH + l * 8);
      half8 s1 = *(const half8*)(xcur + (size_t)e1.x * HH + l * 8);
      half8 s2 = *(const half8*)(xcur + (size_t)e2.x * HH + l * 8);
      half8 s3 = *(const half8*)(xcur + (size_t)e3.x * HH + l * 8);
      float v0 = __int_as_float(e0.y), v1 = __int_as_float(e1.y);
      float v2 = __int_as_float(e2.y), v3 = __int_as_float(e3.y);
      #pragma unroll
      for (int j = 0; j < 8; ++j) {
        a0[j] = fmaf(v0, (float)s0[j], a0[j]);
        a1[j] = fmaf(v1, (float)s1[j], a1[j]);
        a2[j] = fmaf(v2, (float)s2[j], a2[j]);
        a3[j] = fmaf(v3, (float)s3[j], a3[j]);
      }
    }
    for (; k < ke; ++k) {
      int2 e0 = edges[k];
      half8 s0 = *(const half8*)(xcur + (size_t)e0.x * HH + l * 8);
      float v0 = __int_as_float(e0.y);
      #pragma unroll
      for (int j = 0; j < 8; ++j) a0[j] = fmaf(v0, (float)s0[j], a0[j]);
    }
    half8 hv;
    #pragma unroll
    for (int j = 0; j < 8; ++j)
      hv[j] = (_Float16)((a0[j] + a1[j]) + (a2[j] + a3[j]));
    *(half8*)&smem[g * 136 + l * 8] = hv;     // y tile [16][128], stride 136
    __syncthreads();

    // ---- dense epilogue: 16x128 @ 128x128, wave w owns n-tiles {2w, 2w+1} ----
    float4v acc[2];
    acc[0] = (float4v){0.f,0.f,0.f,0.f};
    acc[1] = (float4v){0.f,0.f,0.f,0.f};
    #pragma unroll
    for (int k0 = 0; k0 < HH; k0 += 32) {
      half8 ah = *(const half8*)&smem[lm * 136 + k0 + lq * 8];
      #pragma unroll
      for (int nt = 0; nt < 2; ++nt) {
        half8 bh = *(const half8*)(wt + (((k0 >> 5) * 8) + w * 2 + nt) * 512 + lane * 8);
        acc[nt] = __builtin_amdgcn_mfma_f32_16x16x32_f16(ah, bh, acc[nt], 0, 0, 0);
      }
    }
    float v[2][4];
    float ssp[4] = {0.f, 0.f, 0.f, 0.f};
    #pragma unroll
    for (int nt = 0; nt < 2; ++nt) {
      float bv = bias[w * 32 + nt * 16 + lm];
      #pragma unroll
      for (int rr = 0; rr < 4; ++rr) {
        float t = fmaxf(acc[nt][rr] + bv, 0.f);
        v[nt][rr] = t;
        ssp[rr] += t * t;
      }
    }
    if (DO_L2) {
      #pragma unroll
      for (int m = 1; m < 16; m <<= 1) {
        #pragma unroll
        for (int rr = 0; rr < 4; ++rr) ssp[rr] += __shfl_xor(ssp[rr], m, 64);
      }
      float* sred = (float*)(smem + 16 * 136);       // 64 floats
      if (lm == 0) {
        #pragma unroll
        for (int rr = 0; rr < 4; ++rr) sred[w * 16 + lq * 4 + rr] = ssp[rr];
      }
      __syncthreads();
      #pragma unroll
      for (int rr = 0; rr < 4; ++rr) {
        int rowl = lq * 4 + rr;
        float tot = sred[rowl] + sred[16 + rowl] + sred[32 + rowl] + sred[48 + rowl];
        float sc = 1.f / fmaxf(sqrtf(tot), 1e-12f);
        v[0][rr] *= sc;
        v[1][rr] *= sc;
      }
    }
    #pragma unroll
    for (int rr = 0; rr < 4; ++rr) {
      size_t ro = (size_t)(idx * 16 + lq * 4 + rr) * HH;
      #pragma unroll
      for (int nt = 0; nt < 2; ++nt)
        xnext[ro + w * 32 + nt * 16 + lm] = (_Float16)v[nt][rr];
    }
    return;
  }

  // ---- score role: 32-row tile, wave w owns 64 n-cols ----
  float* Sb = S + (size_t)br * N;
  _Float16* h1s = smem;                 // [32][264]
  const int HS = H2 + 8;
  const int m0 = idx * 32;
  const int wn = w * 64;
  {
    float4v acc[2][4];
    #pragma unroll
    for (int i = 0; i < 2; ++i)
      #pragma unroll
      for (int j = 0; j < 4; ++j) acc[i][j] = (float4v){0.f,0.f,0.f,0.f};
    #pragma unroll
    for (int k0 = 0; k0 < HH; k0 += 32) {
      half8 ah[2], bh[4];
      #pragma unroll
      for (int mt = 0; mt < 2; ++mt)
        ah[mt] = *(const half8*)(xcur + (size_t)(m0 + mt * 16 + lm) * HH + k0 + lq * 8);
      #pragma unroll
      for (int nt = 0; nt < 4; ++nt)
        bh[nt] = *(const half8*)(w1 + (((k0 >> 5) * 16) + (wn >> 4) + nt) * 512 + lane * 8);
      #pragma unroll
      for (int mt = 0; mt < 2; ++mt)
        #pragma unroll
        for (int nt = 0; nt < 4; ++nt)
          acc[mt][nt] = __builtin_amdgcn_mfma_f32_16x16x32_f16(ah[mt], bh[nt], acc[mt][nt], 0, 0, 0);
    }
    float bv[4];
    #pragma unroll
    for (int nt = 0; nt < 4; ++nt) bv[nt] = b1v[wn + nt * 16 + lm];
    #pragma unroll
    for (int mt = 0; mt < 2; ++mt)
      #pragma unroll
      for (int rr = 0; rr < 4; ++rr) {
        int rowl = mt * 16 + lq * 4 + rr;
        #pragma unroll
        for (int nt = 0; nt < 4; ++nt)
          h1s[rowl * HS + wn + nt * 16 + lm] = (_Float16)fmaxf(acc[mt][nt][rr] + bv[nt], 0.f);
      }
  }
  __syncthreads();
  {
    float4v acc[2][4];
    #pragma unroll
    for (int i = 0; i < 2; ++i)
      #pragma unroll
      for (int j = 0; j < 4; ++j) acc[i][j] = (float4v){0.f,0.f,0.f,0.f};
    #pragma unroll
    for (int k0 = 0; k0 < H2; k0 += 32) {
      half8 ah[2], bh[4];
      #pragma unroll
      for (int mt = 0; mt < 2; ++mt)
        ah[mt] = *(const half8*)&h1s[(mt * 16 + lm) * HS + k0 + lq * 8];
      #pragma unroll
      for (int nt = 0; nt < 4; ++nt)
        bh[nt] = *(const half8*)(w2 + (((k0 >> 5) * 16) + (wn >> 4) + nt) * 512 + lane * 8);
      #pragma unroll
      for (int mt = 0; mt < 2; ++mt)
        #pragma unroll
        for (int nt = 0; nt < 4; ++nt)
          acc[mt][nt] = __builtin_amdgcn_mfma_f32_16x16x32_f16(ah[mt], bh[nt], acc[mt][nt], 0, 0, 0);
    }
    float bv[4], wv[4];
    #pragma unroll
    for (int nt = 0; nt < 4; ++nt) {
      int col = wn + nt * 16 + lm;
      bv[nt] = b2v[col]; wv[nt] = w3v[col];
    }
    #pragma unroll
    for (int mt = 0; mt < 2; ++mt)
      #pragma unroll
      for (int rr = 0; rr < 4; ++rr) {
        float p = 0.f;
        #pragma unroll
        for (int nt = 0; nt < 4; ++nt)
          p += fmaxf(acc[mt][nt][rr] + bv[nt], 0.f) * wv[nt];
        p += __shfl_xor(p, 1, 64);
        p += __shfl_xor(p, 2, 64);
        p += __shfl_xor(p, 4, 64);
        p += __shfl_xor(p, 8, 64);
        if (lm == 0) {
          int row = m0 + mt * 16 + lq * 4 + rr;
          if (row < N) atomicAdd(&Sb[row], p);
        }
      }
  }
}

__global__ void final_kernel(const float* __restrict__ s_in, const float* __restrict__ s_out,
                             const float* __restrict__ b3, void* __restrict__ out, int N,
                             const int* __restrict__ dt) {
  int i = blockIdx.x * 256 + threadIdx.x;
  if (i >= N) return;
  float b = 4.f * b3[0];
  float v = (s_in[i] + b) * (s_out[i] + b);
  if (dt[0]) ((unsigned short*)out)[i] = f2bf(v);
  else       ((float*)out)[i] = v;
}

extern "C" void kernel_launch(void* const* d_in, const int* in_sizes, int n_in,
                              void* d_out, int out_size, void* d_ws, size_t ws_size,
                              hipStream_t stream) {
  const int N = NN, E = EE;

  char* ws = (char*)d_ws;
  size_t o = 0;
  auto alloc = [&](size_t bytes) -> void* {
    void* p = ws + o;
    o = (o + bytes + 255) & ~(size_t)255;
    return p;
  };

  int* dt = (int*)alloc(16);
  float* bc[4]; float* l1b; float* l2b; float* w3f; float* l3b;
  for (int i = 0; i < 4; ++i) bc[i] = (float*)alloc(HH * 4);
  l1b = (float*)alloc(H2 * 4);
  l2b = (float*)alloc(H2 * 4);
  w3f = (float*)alloc(H2 * 4);
  l3b = (float*)alloc(4);
  _Float16* l1w_h = (_Float16*)alloc(H2 * HH * 2);
  _Float16* l2w_h = (_Float16*)alloc(H2 * H2 * 2);
  _Float16* Wt_h[3];
  for (int i = 0; i < 3; ++i) Wt_h[i] = (_Float16*)alloc(HH * HH * 2);
  _Float16* w1_h = (_Float16*)alloc((size_t)N * HH * 2);

  const int NP = N + 128;
  const size_t XS = (size_t)NP * HH;
  int* rp    = (int*)alloc(2 * (size_t)(N + 1) * 4);
  int* bcnt  = (int*)alloc(2 * NBUCK * 4);
  int* bbase = (int*)alloc(2 * NBUCK * 4);
  int* gcur  = (int*)alloc(2 * NBUCK * 4);
  int2* binned = (int2*)alloc(2 * (size_t)E * 8);
  int2* edges  = (int2*)alloc(2 * (size_t)E * 8);
  _Float16* x_h  = (_Float16*)alloc(2 * XS * 2);    // ping
  _Float16* tb_h = (_Float16*)alloc(2 * XS * 2);    // pong
  float* sacc = (float*)alloc(2 * (size_t)N * 4);

  dim3 blk(256);
  detect_kernel<<<1, 64, 0, stream>>>((const unsigned int*)d_in[2], dt);

  // merged conversions (w1/w2/wt in fragment-major layout)
  ConvSegs cs;
  const void* srcs[NSEG] = {d_in[7], d_in[9], d_in[11], d_in[13], d_in[15], d_in[17],
                            d_in[18], d_in[19], d_in[14], d_in[16], d_in[8], d_in[10],
                            d_in[12], d_in[6]};
  void* dsts[NSEG] = {bc[0], bc[1], bc[2], bc[3], l1b, l2b, w3f, l3b,
                      l1w_h, l2w_h, Wt_h[0], Wt_h[1], Wt_h[2], w1_h};
  int ns[NSEG] = {HH, HH, HH, HH, H2, H2, H2, 1,
                  H2 * HH, H2 * H2, HH * HH, HH * HH, HH * HH, N * HH};
  int ms[NSEG] = {0, 0, 0, 0, 0, 0, 0, 0, 3, 3, 4, 4, 4, 1};
  int ks[NSEG] = {0, 0, 0, 0, 0, 0, 0, 0, HH, H2, HH, HH, HH, 0};
  int btot = 0;
  for (int i = 0; i < NSEG; ++i) {
    cs.s[i] = srcs[i]; cs.d[i] = dsts[i]; cs.n[i] = ns[i]; cs.mode[i] = ms[i]; cs.kd[i] = ks[i];
    cs.bstart[i] = btot;
    btot += (ns[i] + 255) / 256;
  }
  cs.bstart[NSEG] = btot;
  convall_kernel<<<btot, blk, 0, stream>>>(cs, dt);

  hipMemsetAsync(sacc, 0, 2 * (size_t)N * 4, stream);
  hipMemsetAsync(bcnt, 0, 2 * NBUCK * 4, stream);
  // zero pad rows (score A-frags read up to 47 rows past N)
  hipMemsetAsync(x_h  + (size_t)N * HH, 0, (size_t)128 * HH * 2, stream);
  hipMemsetAsync(x_h  + XS + (size_t)N * HH, 0, (size_t)128 * HH * 2, stream);
  hipMemsetAsync(tb_h + (size_t)N * HH, 0, (size_t)128 * HH * 2, stream);
  hipMemsetAsync(tb_h + XS + (size_t)N * HH, 0, (size_t)128 * HH * 2, stream);

  int sg   = (N + 15) / 16;          // 3125 spmm row-blocks
  int gx32 = (N + 31) / 32;          // 1563 score tiles
  int mg   = ((sg + 1) / 2) * 3;     // 4689: 2 spmm : 1 score interleave
  int bg   = (E + BINCH - 1) / BINCH;
  const size_t FLDS = (size_t)32 * (H2 + 8) * sizeof(_Float16);   // 16896 B

  // ---- CSR build, both branches in parallel ----
  bincount_kernel<<<dim3(bg, 2), blk, 0, stream>>>((const int*)d_in[0], (const int*)d_in[3], bcnt, E);
  bscan_kernel<<<dim3(1, 2), blk, 0, stream>>>(bcnt, bbase, gcur);
  bin_kernel<<<dim3(bg, 2), blk, 0, stream>>>(
      (const int*)d_in[0], (const int*)d_in[3], (const int*)d_in[1], (const int*)d_in[4],
      d_in[2], d_in[5], gcur, binned, E, dt);
  bucket_kernel<<<dim3(NBUCK, 2), blk, 0, stream>>>(bbase, binned, edges, rp, N, E);

  // ---- layer 1: x1 = l2(relu(A@W1 + b1)) ----
  spmm_kernel<1><<<dim3(sg, 2), blk, 0, stream>>>(rp, edges, w1_h, 0, bc[0], x_h, XS, N);

  // ---- layers 2..4 merged with score(x_prev); associativity: A@(xW) = (A@x)@W ----
  fused_kernel<1><<<dim3(mg, 2), blk, FLDS, stream>>>(
      rp, edges, x_h, tb_h, Wt_h[0], bc[1], l1w_h, l2w_h, l1b, l2b, w3f,
      sacc, N, sg, gx32, 1);
  fused_kernel<1><<<dim3(mg, 2), blk, FLDS, stream>>>(
      rp, edges, tb_h, x_h, Wt_h[1], bc[2], l1w_h, l2w_h, l1b, l2b, w3f,
      sacc, N, sg, gx32, 1);
  fused_kernel<0><<<dim3(mg, 2), blk, FLDS, stream>>>(
      rp, edges, x_h, tb_h, Wt_h[2], bc[3], l1w_h, l2w_h, l1b, l2b, w3f,
      sacc, N, sg, gx32, 1);
  // ---- score(x4) only ----
  fused_kernel<0><<<dim3(gx32, 2), blk, FLDS, stream>>>(
      rp, edges, tb_h, nullptr, nullptr, nullptr, l1w_h, l2w_h, l1b, l2b, w3f,
      sacc, N, 0, gx32, 0);

  final_kernel<<<(N + 255) / 256, blk, 0, stream>>>(sacc, sacc + N, l3b, d_out, N, dt);
}